// Round 2
// baseline (755.749 us; speedup 1.0000x reference)
//
#include <hip/hip_runtime.h>

#define Bz  32
#define NQz 1024
#define NKz 1024
#define SCALE 0.04419417382415922f  // 1/sqrt(512)

typedef __bf16 bf16_t;
typedef bf16_t bf16x8 __attribute__((ext_vector_type(8)));
typedef bf16_t bf16x4 __attribute__((ext_vector_type(4)));
typedef float  f32x4  __attribute__((ext_vector_type(4)));

#define MFMA16(a, b, c) __builtin_amdgcn_mfma_f32_16x16x32_bf16(a, b, c, 0, 0, 0)

// ---- fp32 -> bf16 bulk convert (Q and K inputs), 8 elems/thread
__global__ __launch_bounds__(256) void cvt_bf16(const float* __restrict__ Q,
                                                const float* __restrict__ K,
                                                bf16_t* __restrict__ Qb,
                                                bf16_t* __restrict__ Kb) {
  const size_t i = ((size_t)blockIdx.x * 256 + threadIdx.x) * 8;
  const float* src = blockIdx.y ? K : Q;
  bf16_t* dst = blockIdx.y ? Kb : Qb;
  float4 a = *(const float4*)(src + i);
  float4 b = *(const float4*)(src + i + 4);
  bf16x8 r;
  r[0] = (bf16_t)a.x; r[1] = (bf16_t)a.y; r[2] = (bf16_t)a.z; r[3] = (bf16_t)a.w;
  r[4] = (bf16_t)b.x; r[5] = (bf16_t)b.y; r[6] = (bf16_t)b.z; r[7] = (bf16_t)b.w;
  *(bf16x8*)(dst + i) = r;
}

// ---- transpose + bf16-convert the four 512x512 weight matrices: Wt[n][k] = W[k][n]
__global__ void transpose_w(const float* __restrict__ W0, const float* __restrict__ W1,
                            const float* __restrict__ W2, const float* __restrict__ W3,
                            bf16_t* __restrict__ out) {
  __shared__ float tile[32][33];
  const float* W = blockIdx.z == 0 ? W0 : blockIdx.z == 1 ? W1 : blockIdx.z == 2 ? W2 : W3;
  bf16_t* o = out + (size_t)blockIdx.z * 512 * 512;
  const int n0 = blockIdx.x * 32, k0 = blockIdx.y * 32;
  const int tx = threadIdx.x, ty = threadIdx.y;  // (32,8)
  for (int i = 0; i < 4; i++)
    tile[ty + i * 8][tx] = W[(size_t)(k0 + ty + i * 8) * 512 + n0 + tx];
  __syncthreads();
  for (int i = 0; i < 4; i++)
    o[(size_t)(n0 + ty + i * 8) * 512 + k0 + tx] = (bf16_t)tile[tx][ty + i * 8];
}

// ---- 128x128 bf16 MFMA GEMM. A bf16 [32768][512], Wt bf16 [512n][512k].
// MODE 0: C = bf16((A@W + bias) * mult)    MODE 1: C = bf16(A + relu(A@W + bias))
template <int MODE>
__global__ __launch_bounds__(256) void gemm_k(const bf16_t* __restrict__ A,
                                              const bf16_t* __restrict__ Wt,
                                              const float* __restrict__ bias, float mult,
                                              bf16_t* __restrict__ C) {
  __shared__ __align__(16) bf16_t As[128][40];
  __shared__ __align__(16) bf16_t Bs[128][40];
  const int t = threadIdx.x;
  const int wave = t >> 6, lane = t & 63;
  const int quad = lane >> 4, l16 = lane & 15;
  const int wm = wave & 1, wn = wave >> 1;
  const int m0 = blockIdx.x * 128, n0 = blockIdx.y * 128;
  const int r = t >> 1, half = t & 1;

  f32x4 acc[4][4] = {};

  for (int k0 = 0; k0 < 512; k0 += 32) {
    __syncthreads();
    {
      const bf16_t* ap = A + (size_t)(m0 + r) * 512 + k0 + half * 16;
      *(bf16x8*)&As[r][half * 16 + 0] = *(const bf16x8*)(ap + 0);
      *(bf16x8*)&As[r][half * 16 + 8] = *(const bf16x8*)(ap + 8);
      const bf16_t* bp = Wt + (size_t)(n0 + r) * 512 + k0 + half * 16;
      *(bf16x8*)&Bs[r][half * 16 + 0] = *(const bf16x8*)(bp + 0);
      *(bf16x8*)&Bs[r][half * 16 + 8] = *(const bf16x8*)(bp + 8);
    }
    __syncthreads();
    bf16x8 af[4], bfv[4];
    for (int mt = 0; mt < 4; mt++)
      af[mt] = *(const bf16x8*)&As[wm * 64 + mt * 16 + l16][quad * 8];
    for (int nt = 0; nt < 4; nt++)
      bfv[nt] = *(const bf16x8*)&Bs[wn * 64 + nt * 16 + l16][quad * 8];
    for (int mt = 0; mt < 4; mt++)
      for (int nt = 0; nt < 4; nt++)
        acc[mt][nt] = MFMA16(af[mt], bfv[nt], acc[mt][nt]);
  }

  for (int mt = 0; mt < 4; mt++) {
    for (int nt = 0; nt < 4; nt++) {
      const int row = m0 + wm * 64 + mt * 16 + quad * 4;
      const int col = n0 + wn * 64 + nt * 16 + l16;
      const float bv = bias[col];
      for (int rg = 0; rg < 4; rg++) {
        float v = acc[mt][nt][rg] + bv;
        if (MODE == 0) {
          C[(size_t)(row + rg) * 512 + col] = (bf16_t)(v * mult);
        } else {
          float x = (float)A[(size_t)(row + rg) * 512 + col];
          C[(size_t)(row + rg) * 512 + col] = (bf16_t)(x + fmaxf(v, 0.f));
        }
      }
    }
  }
}

// ---- stats: l_k = sum_q exp(s[q,k]) (kp pre-scaled by 1/sqrt(512));
// writes Vt[hb][d][k] = V[k][d] / l_k (transposed, scaled). Grid (NK/128, B, H).
// Scores computed transposed (m=k via A-frag from kp, n=q via B-frag from qp) --
// all fragments loaded DIRECTLY from global (no LDS staging, no barriers in loop).
__global__ __launch_bounds__(256) void attn_stats(const bf16_t* __restrict__ qp,
                                                  const bf16_t* __restrict__ kp,
                                                  const bf16_t* __restrict__ vp,
                                                  bf16_t* __restrict__ Vt) {
  __shared__ __align__(16) bf16_t Vs[128][72];
  __shared__ float ls[128];
  const int t = threadIdx.x;
  const int wave = t >> 6, lane = t & 63;
  const int quad = lane >> 4, l16 = lane & 15;
  const int kb = blockIdx.x * 128;
  const int b = blockIdx.y, h = blockIdx.z;
  const bf16_t* qbase = qp + (size_t)b * NQz * 512 + h * 64;
  const bf16_t* kbase = kp + (size_t)b * NKz * 512 + h * 64;

  // stage V block for the later transpose (overlaps with MFMA loop)
  {
    const int r = t >> 1, half = t & 1;
    const bf16_t* vr = vp + (size_t)b * NKz * 512 + (size_t)(kb + r) * 512 + h * 64 + half * 32;
    *(bf16x8*)&Vs[r][half * 32 + 0]  = *(const bf16x8*)(vr + 0);
    *(bf16x8*)&Vs[r][half * 32 + 8]  = *(const bf16x8*)(vr + 8);
    *(bf16x8*)&Vs[r][half * 32 + 16] = *(const bf16x8*)(vr + 16);
    *(bf16x8*)&Vs[r][half * 32 + 24] = *(const bf16x8*)(vr + 24);
  }

  // preload K A-frags (wave-private 32 k-rows)
  bf16x8 aK[2][2];
  for (int mt = 0; mt < 2; mt++) {
    const bf16_t* kr = kbase + (size_t)(kb + wave * 32 + mt * 16 + l16) * 512 + quad * 8;
    aK[mt][0] = *(const bf16x8*)kr;
    aK[mt][1] = *(const bf16x8*)(kr + 32);
  }

  f32x4 lacc[2] = {};
  for (int q0 = 0; q0 < NQz; q0 += 64) {
    for (int nt = 0; nt < 4; nt++) {
      const bf16_t* qr = qbase + (size_t)(q0 + nt * 16 + l16) * 512 + quad * 8;
      bf16x8 b0 = *(const bf16x8*)qr;
      bf16x8 b1 = *(const bf16x8*)(qr + 32);
      for (int mt = 0; mt < 2; mt++) {
        f32x4 s = {0.f, 0.f, 0.f, 0.f};
        s = MFMA16(aK[mt][0], b0, s);
        s = MFMA16(aK[mt][1], b1, s);
        lacc[mt][0] += __expf(s[0]);
        lacc[mt][1] += __expf(s[1]);
        lacc[mt][2] += __expf(s[2]);
        lacc[mt][3] += __expf(s[3]);
      }
    }
  }
  // reduce over q (16 columns spread across l16 lanes of same quad)
  for (int mt = 0; mt < 2; mt++) {
    for (int rg = 0; rg < 4; rg++) {
      float v = lacc[mt][rg];
      v += __shfl_xor(v, 1);
      v += __shfl_xor(v, 2);
      v += __shfl_xor(v, 4);
      v += __shfl_xor(v, 8);
      if (l16 == 0) ls[wave * 32 + mt * 16 + quad * 4 + rg] = 1.0f / v;
    }
  }
  __syncthreads();
  // transpose + scale: Vt[hb][d][kb..kb+127]
  const int d = t >> 2, kc = (t & 3) * 32;
  const size_t hb = (size_t)h * Bz + b;
  bf16_t* vtr = Vt + hb * 64 * 1024 + (size_t)d * 1024 + kb + kc;
  for (int c = 0; c < 4; c++) {
    bf16x8 o;
    for (int j = 0; j < 8; j++)
      o[j] = (bf16_t)((float)Vs[kc + c * 8 + j][d] * ls[kc + c * 8 + j]);
    *(bf16x8*)(vtr + c * 8) = o;
  }
}

// ---- attn_out: O[q,d] = sum_k exp(s[q,k]) * Vt[d,k]  (Vt already /l_k; residual in LN0).
// Grid (NQ/128, B, H). Scores computed transposed so P packs to b64 LDS writes and
// PV A-frags are b128 LDS reads. Ps rows are wave-private -> NO barriers at all.
__global__ __launch_bounds__(256) void attn_out(const bf16_t* __restrict__ qp,
                                                const bf16_t* __restrict__ kp,
                                                const bf16_t* __restrict__ Vt,
                                                bf16_t* __restrict__ oh) {
  __shared__ __align__(16) bf16_t Ps[128][72];
  const int t = threadIdx.x;
  const int wave = t >> 6, lane = t & 63;
  const int quad = lane >> 4, l16 = lane & 15;
  const int q0 = blockIdx.x * 128;
  const int b = blockIdx.y, h = blockIdx.z;
  const bf16_t* qbase = qp + (size_t)b * NQz * 512 + h * 64;
  const bf16_t* kbase = kp + (size_t)b * NKz * 512 + h * 64;
  const size_t hb = (size_t)h * Bz + b;
  const bf16_t* vtbase = Vt + hb * 64 * 1024;

  // preload Q B-frags (wave-private 32 q-rows)
  bf16x8 bQ[2][2];
  for (int nt = 0; nt < 2; nt++) {
    const bf16_t* qr = qbase + (size_t)(q0 + wave * 32 + nt * 16 + l16) * 512 + quad * 8;
    bQ[nt][0] = *(const bf16x8*)qr;
    bQ[nt][1] = *(const bf16x8*)(qr + 32);
  }

  f32x4 acc[2][4] = {};
  for (int kk = 0; kk < NKz; kk += 64) {
    // S^T: m = k (A-frag from kp global), n = q. C rows = 4 consecutive k -> b64 pack.
    for (int mt = 0; mt < 4; mt++) {
      const bf16_t* kr = kbase + (size_t)(kk + mt * 16 + l16) * 512 + quad * 8;
      bf16x8 a0 = *(const bf16x8*)kr;
      bf16x8 a1 = *(const bf16x8*)(kr + 32);
      for (int nt = 0; nt < 2; nt++) {
        f32x4 s = {0.f, 0.f, 0.f, 0.f};
        s = MFMA16(a0, bQ[nt][0], s);
        s = MFMA16(a1, bQ[nt][1], s);
        bf16x4 pk;
        pk[0] = (bf16_t)__expf(s[0]);
        pk[1] = (bf16_t)__expf(s[1]);
        pk[2] = (bf16_t)__expf(s[2]);
        pk[3] = (bf16_t)__expf(s[3]);
        *(bf16x4*)&Ps[wave * 32 + nt * 16 + l16][mt * 16 + quad * 4] = pk;
      }
    }
    // PV: A-frag = Ps rows (b128), B-frag = Vt rows direct from global.
    bf16x8 aP[2][2];
    for (int mt = 0; mt < 2; mt++) {
      aP[mt][0] = *(const bf16x8*)&Ps[wave * 32 + mt * 16 + l16][quad * 8];
      aP[mt][1] = *(const bf16x8*)&Ps[wave * 32 + mt * 16 + l16][quad * 8 + 32];
    }
    for (int nd = 0; nd < 4; nd++) {
      const bf16_t* vr = vtbase + (size_t)(nd * 16 + l16) * 1024 + kk + quad * 8;
      bf16x8 b0 = *(const bf16x8*)vr;
      bf16x8 b1 = *(const bf16x8*)(vr + 32);
      for (int mt = 0; mt < 2; mt++) {
        acc[mt][nd] = MFMA16(aP[mt][0], b0, acc[mt][nd]);
        acc[mt][nd] = MFMA16(aP[mt][1], b1, acc[mt][nd]);
      }
    }
  }
  // epilogue: stage wave-private rows into Ps, then vector global stores
  for (int mt = 0; mt < 2; mt++)
    for (int nd = 0; nd < 4; nd++)
      for (int rg = 0; rg < 4; rg++)
        Ps[wave * 32 + mt * 16 + quad * 4 + rg][nd * 16 + l16] = (bf16_t)acc[mt][nd][rg];
  const int row = wave * 32 + (lane >> 1), cc = (lane & 1) * 32;
  bf16_t* orow = oh + ((size_t)b * NQz + q0 + row) * 512 + h * 64 + cc;
  for (int c = 0; c < 4; c++)
    *(bf16x8*)(orow + c * 8) = *(const bf16x8*)&Ps[row][cc + c * 8];
}

// ---- LayerNorm over 512 cols, one wave per row, bf16 in.
// RES: add bf16 residual pre-norm. F32OUT: write f32 (else bf16).
template <int RES, int F32OUT>
__global__ __launch_bounds__(256) void ln_k(const bf16_t* __restrict__ x,
                                            const bf16_t* __restrict__ res,
                                            const float* __restrict__ g,
                                            const float* __restrict__ be,
                                            bf16_t* __restrict__ yb,
                                            float* __restrict__ yf) {
  const int wave = threadIdx.x >> 6, lane = threadIdx.x & 63;
  const size_t row = (size_t)blockIdx.x * 4 + wave;
  bf16x8 xv = *(const bf16x8*)(x + row * 512 + lane * 8);
  float xf[8];
  for (int i = 0; i < 8; i++) xf[i] = (float)xv[i];
  if (RES) {
    bf16x8 rv = *(const bf16x8*)(res + row * 512 + lane * 8);
    for (int i = 0; i < 8; i++) xf[i] += (float)rv[i];
  }
  float s = 0.f, sq = 0.f;
  for (int i = 0; i < 8; i++) { s += xf[i]; sq += xf[i] * xf[i]; }
  for (int off = 1; off < 64; off <<= 1) {
    s += __shfl_xor(s, off);
    sq += __shfl_xor(sq, off);
  }
  const float mu = s * (1.0f / 512.0f);
  const float var = sq * (1.0f / 512.0f) - mu * mu;
  const float rstd = rsqrtf(var + 1e-5f);
  float4 gv0 = *(const float4*)(g + lane * 8);
  float4 gv1 = *(const float4*)(g + lane * 8 + 4);
  float4 bv0 = *(const float4*)(be + lane * 8);
  float4 bv1 = *(const float4*)(be + lane * 8 + 4);
  float gg[8] = {gv0.x, gv0.y, gv0.z, gv0.w, gv1.x, gv1.y, gv1.z, gv1.w};
  float bb[8] = {bv0.x, bv0.y, bv0.z, bv0.w, bv1.x, bv1.y, bv1.z, bv1.w};
  float o[8];
  for (int i = 0; i < 8; i++) o[i] = (xf[i] - mu) * rstd * gg[i] + bb[i];
  if (F32OUT) {
    float4 o0 = {o[0], o[1], o[2], o[3]}, o1 = {o[4], o[5], o[6], o[7]};
    *(float4*)(yf + row * 512 + lane * 8) = o0;
    *(float4*)(yf + row * 512 + lane * 8 + 4) = o1;
  } else {
    bf16x8 ov;
    for (int i = 0; i < 8; i++) ov[i] = (bf16_t)o[i];
    *(bf16x8*)(yb + row * 512 + lane * 8) = ov;
  }
}

extern "C" void kernel_launch(void* const* d_in, const int* in_sizes, int n_in,
                              void* d_out, int out_size, void* d_ws, size_t ws_size,
                              hipStream_t stream) {
  (void)in_sizes; (void)n_in; (void)out_size; (void)ws_size;
  const float* Q   = (const float*)d_in[0];
  const float* K   = (const float*)d_in[1];
  const float* Wq  = (const float*)d_in[2];
  const float* bq  = (const float*)d_in[3];
  const float* Wk  = (const float*)d_in[4];
  const float* bk  = (const float*)d_in[5];
  const float* Wv  = (const float*)d_in[6];
  const float* bv  = (const float*)d_in[7];
  const float* Wo  = (const float*)d_in[8];
  const float* bo  = (const float*)d_in[9];
  const float* g0  = (const float*)d_in[10];
  const float* be0 = (const float*)d_in[11];
  const float* g1  = (const float*)d_in[12];
  const float* be1 = (const float*)d_in[13];
  float* outp = (float*)d_out;

  char* w = (char*)d_ws;
  bf16_t* Wt  = (bf16_t*)w;                    // 2 MB (4 x 512x512 bf16)
  bf16_t* Qb  = (bf16_t*)(w + (2ull << 20));   // 32 MB  (input Q bf16)   -> dead after qp
  bf16_t* Kb  = (bf16_t*)(w + (34ull << 20));  // 32 MB  (input K bf16)   -> dead after vp
  bf16_t* qp  = (bf16_t*)(w + (66ull << 20));  // 32 MB  (Q proj; residual source)
  bf16_t* kp  = (bf16_t*)(w + (98ull << 20));  // 32 MB  (K proj, pre-scaled)
  bf16_t* vp  = (bf16_t*)(w + (130ull << 20)); // 32 MB  (V proj)         -> dead after stats
  bf16_t* Vt  = Kb;                            // reuse: V'/l transposed [hb][64][1024]
  bf16_t* ohb = Qb;                            // reuse: attn out (no resid)
  bf16_t* x0b = vp;                            // reuse: LN0 out
  bf16_t* oh2 = kp;                            // reuse: out-proj+relu+resid

  cvt_bf16<<<dim3(8192, 2), 256, 0, stream>>>(Q, K, Qb, Kb);
  transpose_w<<<dim3(16, 16, 4), dim3(32, 8), 0, stream>>>(Wq, Wk, Wv, Wo, Wt);
  gemm_k<0><<<dim3(256, 4), 256, 0, stream>>>(Qb, Wt + 0 * (1 << 18), bq, 1.0f, qp);
  gemm_k<0><<<dim3(256, 4), 256, 0, stream>>>(Kb, Wt + 1 * (1 << 18), bk, SCALE, kp);
  gemm_k<0><<<dim3(256, 4), 256, 0, stream>>>(Kb, Wt + 2 * (1 << 18), bv, 1.0f, vp);
  attn_stats<<<dim3(8, 32, 8), 256, 0, stream>>>(qp, kp, vp, Vt);
  attn_out<<<dim3(8, 32, 8), 256, 0, stream>>>(qp, kp, Vt, ohb);
  ln_k<1, 0><<<8192, 256, 0, stream>>>(ohb, qp, g0, be0, x0b, nullptr);
  gemm_k<1><<<dim3(256, 4), 256, 0, stream>>>(x0b, Wt + 3 * (1 << 18), bo, 1.0f, oh2);
  ln_k<0, 1><<<8192, 256, 0, stream>>>(oh2, nullptr, g1, be1, nullptr, outp);
}

// Round 3
// 514.531 us; speedup vs baseline: 1.4688x; 1.4688x over previous
//
#include <hip/hip_runtime.h>

#define Bz  32
#define NQz 1024
#define NKz 1024
#define SCALE 0.04419417382415922f  // 1/sqrt(512)

typedef __bf16 bf16_t;
typedef bf16_t bf16x8 __attribute__((ext_vector_type(8)));
typedef bf16_t bf16x4 __attribute__((ext_vector_type(4)));
typedef float  f32x4  __attribute__((ext_vector_type(4)));

#define MFMA16(a, b, c) __builtin_amdgcn_mfma_f32_16x16x32_bf16(a, b, c, 0, 0, 0)

// ---- fp32 -> bf16 bulk convert (Q and K inputs), 8 elems/thread
__global__ __launch_bounds__(256) void cvt_bf16(const float* __restrict__ Q,
                                                const float* __restrict__ K,
                                                bf16_t* __restrict__ Qb,
                                                bf16_t* __restrict__ Kb) {
  const size_t i = ((size_t)blockIdx.x * 256 + threadIdx.x) * 8;
  const float* src = blockIdx.y ? K : Q;
  bf16_t* dst = blockIdx.y ? Kb : Qb;
  float4 a = *(const float4*)(src + i);
  float4 b = *(const float4*)(src + i + 4);
  bf16x8 r;
  r[0] = (bf16_t)a.x; r[1] = (bf16_t)a.y; r[2] = (bf16_t)a.z; r[3] = (bf16_t)a.w;
  r[4] = (bf16_t)b.x; r[5] = (bf16_t)b.y; r[6] = (bf16_t)b.z; r[7] = (bf16_t)b.w;
  *(bf16x8*)(dst + i) = r;
}

// ---- transpose + bf16-convert the four 512x512 weight matrices: Wt[n][k] = W[k][n]
__global__ void transpose_w(const float* __restrict__ W0, const float* __restrict__ W1,
                            const float* __restrict__ W2, const float* __restrict__ W3,
                            bf16_t* __restrict__ out) {
  __shared__ float tile[32][33];
  const float* W = blockIdx.z == 0 ? W0 : blockIdx.z == 1 ? W1 : blockIdx.z == 2 ? W2 : W3;
  bf16_t* o = out + (size_t)blockIdx.z * 512 * 512;
  const int n0 = blockIdx.x * 32, k0 = blockIdx.y * 32;
  const int tx = threadIdx.x, ty = threadIdx.y;  // (32,8)
  for (int i = 0; i < 4; i++)
    tile[ty + i * 8][tx] = W[(size_t)(k0 + ty + i * 8) * 512 + n0 + tx];
  __syncthreads();
  for (int i = 0; i < 4; i++)
    o[(size_t)(n0 + ty + i * 8) * 512 + k0 + tx] = (bf16_t)tile[tx][ty + i * 8];
}

// ---- 128x128 bf16 MFMA GEMM. A bf16 [32768][512], Wt bf16 [512n][512k].
// MODE 0: C = bf16((A@W + bias) * mult)    MODE 1: C = bf16(A + relu(A@W + bias))
template <int MODE>
__global__ __launch_bounds__(256) void gemm_k(const bf16_t* __restrict__ A,
                                              const bf16_t* __restrict__ Wt,
                                              const float* __restrict__ bias, float mult,
                                              bf16_t* __restrict__ C) {
  __shared__ __align__(16) bf16_t As[128][40];
  __shared__ __align__(16) bf16_t Bs[128][40];
  const int t = threadIdx.x;
  const int wave = t >> 6, lane = t & 63;
  const int quad = lane >> 4, l16 = lane & 15;
  const int wm = wave & 1, wn = wave >> 1;
  const int m0 = blockIdx.x * 128, n0 = blockIdx.y * 128;
  const int r = t >> 1, half = t & 1;

  f32x4 acc[4][4] = {};

  for (int k0 = 0; k0 < 512; k0 += 32) {
    __syncthreads();
    {
      const bf16_t* ap = A + (size_t)(m0 + r) * 512 + k0 + half * 16;
      *(bf16x8*)&As[r][half * 16 + 0] = *(const bf16x8*)(ap + 0);
      *(bf16x8*)&As[r][half * 16 + 8] = *(const bf16x8*)(ap + 8);
      const bf16_t* bp = Wt + (size_t)(n0 + r) * 512 + k0 + half * 16;
      *(bf16x8*)&Bs[r][half * 16 + 0] = *(const bf16x8*)(bp + 0);
      *(bf16x8*)&Bs[r][half * 16 + 8] = *(const bf16x8*)(bp + 8);
    }
    __syncthreads();
    bf16x8 af[4], bfv[4];
    for (int mt = 0; mt < 4; mt++)
      af[mt] = *(const bf16x8*)&As[wm * 64 + mt * 16 + l16][quad * 8];
    for (int nt = 0; nt < 4; nt++)
      bfv[nt] = *(const bf16x8*)&Bs[wn * 64 + nt * 16 + l16][quad * 8];
    for (int mt = 0; mt < 4; mt++)
      for (int nt = 0; nt < 4; nt++)
        acc[mt][nt] = MFMA16(af[mt], bfv[nt], acc[mt][nt]);
  }

  for (int mt = 0; mt < 4; mt++) {
    for (int nt = 0; nt < 4; nt++) {
      const int row = m0 + wm * 64 + mt * 16 + quad * 4;
      const int col = n0 + wn * 64 + nt * 16 + l16;
      const float bv = bias[col];
      for (int rg = 0; rg < 4; rg++) {
        float v = acc[mt][nt][rg] + bv;
        if (MODE == 0) {
          C[(size_t)(row + rg) * 512 + col] = (bf16_t)(v * mult);
        } else {
          float x = (float)A[(size_t)(row + rg) * 512 + col];
          C[(size_t)(row + rg) * 512 + col] = (bf16_t)(x + fmaxf(v, 0.f));
        }
      }
    }
  }
}

// ---- stats: l_k = sum_q exp(s[q,k]) (kp pre-scaled by 1/sqrt(512));
// writes Vt[hb][d][k] = V[k][d] / l_k (transposed, scaled).
// Grid 2048 (XCD-swizzled). Scores transposed (m=k, n=q). K A-frags in regs,
// Q tiles staged in LDS (coalesced), V block staged once for the epilogue transpose.
__global__ __launch_bounds__(256) void attn_stats(const bf16_t* __restrict__ qp,
                                                  const bf16_t* __restrict__ kp,
                                                  const bf16_t* __restrict__ vp,
                                                  bf16_t* __restrict__ Vt) {
  __shared__ __align__(16) bf16_t Vs[128][72];
  __shared__ __align__(16) bf16_t Qs[64][72];
  __shared__ float ls[128];
  const int t = threadIdx.x;
  const int wave = t >> 6, lane = t & 63;
  const int quad = lane >> 4, l16 = lane & 15;
  const int id = blockIdx.x;
  const int kb = ((id >> 3) & 7) * 128;
  const int hb = (id & 7) * 32 + (id >> 6);   // all 8 k-blocks of one (b,h) on one XCD
  const int h = hb >> 5, b = hb & 31;
  const bf16_t* qbase = qp + (size_t)b * NQz * 512 + h * 64;
  const bf16_t* kbase = kp + (size_t)b * NKz * 512 + h * 64;

  // stage V block for the later transpose (no barrier needed until after loop)
  {
    const int r = t >> 1, half = t & 1;
    const bf16_t* vr = vp + (size_t)b * NKz * 512 + (size_t)(kb + r) * 512 + h * 64 + half * 32;
    *(bf16x8*)&Vs[r][half * 32 + 0]  = *(const bf16x8*)(vr + 0);
    *(bf16x8*)&Vs[r][half * 32 + 8]  = *(const bf16x8*)(vr + 8);
    *(bf16x8*)&Vs[r][half * 32 + 16] = *(const bf16x8*)(vr + 16);
    *(bf16x8*)&Vs[r][half * 32 + 24] = *(const bf16x8*)(vr + 24);
  }

  // preload K A-frags (wave-private 32 k-rows)
  bf16x8 aK[2][2];
  for (int mt = 0; mt < 2; mt++) {
    const bf16_t* kr = kbase + (size_t)(kb + wave * 32 + mt * 16 + l16) * 512 + quad * 8;
    aK[mt][0] = *(const bf16x8*)kr;
    aK[mt][1] = *(const bf16x8*)(kr + 32);
  }

  const int sr = t >> 2, sc = (t & 3) * 16;
  f32x4 lacc[2] = {};
  for (int q0 = 0; q0 < NQz; q0 += 64) {
    __syncthreads();
    {
      const bf16_t* qrr = qbase + (size_t)(q0 + sr) * 512 + sc;
      *(bf16x8*)&Qs[sr][sc + 0] = *(const bf16x8*)(qrr + 0);
      *(bf16x8*)&Qs[sr][sc + 8] = *(const bf16x8*)(qrr + 8);
    }
    __syncthreads();
    for (int nt = 0; nt < 4; nt++) {
      bf16x8 b0 = *(const bf16x8*)&Qs[nt * 16 + l16][quad * 8];
      bf16x8 b1 = *(const bf16x8*)&Qs[nt * 16 + l16][quad * 8 + 32];
      for (int mt = 0; mt < 2; mt++) {
        f32x4 s = {0.f, 0.f, 0.f, 0.f};
        s = MFMA16(aK[mt][0], b0, s);
        s = MFMA16(aK[mt][1], b1, s);
        lacc[mt][0] += __expf(s[0]);
        lacc[mt][1] += __expf(s[1]);
        lacc[mt][2] += __expf(s[2]);
        lacc[mt][3] += __expf(s[3]);
      }
    }
  }
  // reduce over q (16 columns spread across l16 lanes of same quad)
  for (int mt = 0; mt < 2; mt++) {
    for (int rg = 0; rg < 4; rg++) {
      float v = lacc[mt][rg];
      v += __shfl_xor(v, 1);
      v += __shfl_xor(v, 2);
      v += __shfl_xor(v, 4);
      v += __shfl_xor(v, 8);
      if (l16 == 0) ls[wave * 32 + mt * 16 + quad * 4 + rg] = 1.0f / v;
    }
  }
  __syncthreads();
  // transpose + scale: Vt[hb][d][kb..kb+127]
  const int d = t >> 2, kc = (t & 3) * 32;
  bf16_t* vtr = Vt + (size_t)hb * 64 * 1024 + (size_t)d * 1024 + kb + kc;
  for (int c = 0; c < 4; c++) {
    bf16x8 o;
    for (int j = 0; j < 8; j++)
      o[j] = (bf16_t)((float)Vs[kc + c * 8 + j][d] * ls[kc + c * 8 + j]);
    *(bf16x8*)(vtr + c * 8) = o;
  }
}

// ---- attn_out: O[q,d] = sum_k exp(s[q,k]) * Vt[d,k]  (Vt already /l_k; residual in LN0).
// Grid 2048 (XCD-swizzled). K-tile + Vt-tile staged in LDS (coalesced, 2-barrier loop);
// Q B-frags in regs; P via wave-private Ps rows (b64 writes, no extra barrier).
__global__ __launch_bounds__(256) void attn_out(const bf16_t* __restrict__ qp,
                                                const bf16_t* __restrict__ kp,
                                                const bf16_t* __restrict__ Vt,
                                                bf16_t* __restrict__ oh) {
  __shared__ __align__(16) bf16_t Ks[64][72];
  __shared__ __align__(16) bf16_t Vts[64][72];
  __shared__ __align__(16) bf16_t Ps[128][72];
  const int t = threadIdx.x;
  const int wave = t >> 6, lane = t & 63;
  const int quad = lane >> 4, l16 = lane & 15;
  const int id = blockIdx.x;
  const int qt = (id >> 3) & 7;
  const int hb = (id & 7) * 32 + (id >> 6);   // all 8 q-tiles of one (b,h) on one XCD
  const int h = hb >> 5, b = hb & 31;
  const int q0 = qt * 128;
  const bf16_t* qbase = qp + (size_t)b * NQz * 512 + h * 64;
  const bf16_t* kbase = kp + (size_t)b * NKz * 512 + h * 64;
  const bf16_t* vtbase = Vt + (size_t)hb * 64 * 1024;

  // preload Q B-frags (wave-private 32 q-rows)
  bf16x8 bQ[2][2];
  for (int nt = 0; nt < 2; nt++) {
    const bf16_t* qr = qbase + (size_t)(q0 + wave * 32 + nt * 16 + l16) * 512 + quad * 8;
    bQ[nt][0] = *(const bf16x8*)qr;
    bQ[nt][1] = *(const bf16x8*)(qr + 32);
  }

  const int sr = t >> 2, sc = (t & 3) * 16;
  f32x4 acc[2][4] = {};
  for (int kk = 0; kk < NKz; kk += 64) {
    __syncthreads();
    {
      const bf16_t* krr = kbase + (size_t)(kk + sr) * 512 + sc;
      *(bf16x8*)&Ks[sr][sc + 0] = *(const bf16x8*)(krr + 0);
      *(bf16x8*)&Ks[sr][sc + 8] = *(const bf16x8*)(krr + 8);
      const bf16_t* vrr = vtbase + (size_t)sr * 1024 + kk + sc;
      *(bf16x8*)&Vts[sr][sc + 0] = *(const bf16x8*)(vrr + 0);
      *(bf16x8*)&Vts[sr][sc + 8] = *(const bf16x8*)(vrr + 8);
    }
    __syncthreads();
    // S^T: m = k (A-frag from Ks), n = q (B-frag regs). C rows = 4 consecutive k -> b64 pack.
    for (int mt = 0; mt < 4; mt++) {
      bf16x8 a0 = *(const bf16x8*)&Ks[mt * 16 + l16][quad * 8];
      bf16x8 a1 = *(const bf16x8*)&Ks[mt * 16 + l16][quad * 8 + 32];
      for (int nt = 0; nt < 2; nt++) {
        f32x4 s = {0.f, 0.f, 0.f, 0.f};
        s = MFMA16(a0, bQ[nt][0], s);
        s = MFMA16(a1, bQ[nt][1], s);
        bf16x4 pk;
        pk[0] = (bf16_t)__expf(s[0]);
        pk[1] = (bf16_t)__expf(s[1]);
        pk[2] = (bf16_t)__expf(s[2]);
        pk[3] = (bf16_t)__expf(s[3]);
        *(bf16x4*)&Ps[wave * 32 + nt * 16 + l16][mt * 16 + quad * 4] = pk;
      }
    }
    // PV: A-frag = Ps rows (wave-private, b128), B-frag = Vts rows (b128).
    bf16x8 aP[2][2];
    for (int mt = 0; mt < 2; mt++) {
      aP[mt][0] = *(const bf16x8*)&Ps[wave * 32 + mt * 16 + l16][quad * 8];
      aP[mt][1] = *(const bf16x8*)&Ps[wave * 32 + mt * 16 + l16][quad * 8 + 32];
    }
    for (int nd = 0; nd < 4; nd++) {
      bf16x8 b0 = *(const bf16x8*)&Vts[nd * 16 + l16][quad * 8];
      bf16x8 b1 = *(const bf16x8*)&Vts[nd * 16 + l16][quad * 8 + 32];
      for (int mt = 0; mt < 2; mt++) {
        acc[mt][nd] = MFMA16(aP[mt][0], b0, acc[mt][nd]);
        acc[mt][nd] = MFMA16(aP[mt][1], b1, acc[mt][nd]);
      }
    }
  }
  // epilogue: stage wave-private rows into Ps, then vector global stores
  for (int mt = 0; mt < 2; mt++)
    for (int nd = 0; nd < 4; nd++)
      for (int rg = 0; rg < 4; rg++)
        Ps[wave * 32 + mt * 16 + quad * 4 + rg][nd * 16 + l16] = (bf16_t)acc[mt][nd][rg];
  const int row = wave * 32 + (lane >> 1), cc = (lane & 1) * 32;
  bf16_t* orow = oh + ((size_t)b * NQz + q0 + row) * 512 + h * 64 + cc;
  for (int c = 0; c < 4; c++)
    *(bf16x8*)(orow + c * 8) = *(const bf16x8*)&Ps[row][cc + c * 8];
}

// ---- LayerNorm over 512 cols, one wave per row, bf16 in.
// RES: add bf16 residual pre-norm. F32OUT: write f32 (else bf16).
template <int RES, int F32OUT>
__global__ __launch_bounds__(256) void ln_k(const bf16_t* __restrict__ x,
                                            const bf16_t* __restrict__ res,
                                            const float* __restrict__ g,
                                            const float* __restrict__ be,
                                            bf16_t* __restrict__ yb,
                                            float* __restrict__ yf) {
  const int wave = threadIdx.x >> 6, lane = threadIdx.x & 63;
  const size_t row = (size_t)blockIdx.x * 4 + wave;
  bf16x8 xv = *(const bf16x8*)(x + row * 512 + lane * 8);
  float xf[8];
  for (int i = 0; i < 8; i++) xf[i] = (float)xv[i];
  if (RES) {
    bf16x8 rv = *(const bf16x8*)(res + row * 512 + lane * 8);
    for (int i = 0; i < 8; i++) xf[i] += (float)rv[i];
  }
  float s = 0.f, sq = 0.f;
  for (int i = 0; i < 8; i++) { s += xf[i]; sq += xf[i] * xf[i]; }
  for (int off = 1; off < 64; off <<= 1) {
    s += __shfl_xor(s, off);
    sq += __shfl_xor(sq, off);
  }
  const float mu = s * (1.0f / 512.0f);
  const float var = sq * (1.0f / 512.0f) - mu * mu;
  const float rstd = rsqrtf(var + 1e-5f);
  float4 gv0 = *(const float4*)(g + lane * 8);
  float4 gv1 = *(const float4*)(g + lane * 8 + 4);
  float4 bv0 = *(const float4*)(be + lane * 8);
  float4 bv1 = *(const float4*)(be + lane * 8 + 4);
  float gg[8] = {gv0.x, gv0.y, gv0.z, gv0.w, gv1.x, gv1.y, gv1.z, gv1.w};
  float bb[8] = {bv0.x, bv0.y, bv0.z, bv0.w, bv1.x, bv1.y, bv1.z, bv1.w};
  float o[8];
  for (int i = 0; i < 8; i++) o[i] = (xf[i] - mu) * rstd * gg[i] + bb[i];
  if (F32OUT) {
    float4 o0 = {o[0], o[1], o[2], o[3]}, o1 = {o[4], o[5], o[6], o[7]};
    *(float4*)(yf + row * 512 + lane * 8) = o0;
    *(float4*)(yf + row * 512 + lane * 8 + 4) = o1;
  } else {
    bf16x8 ov;
    for (int i = 0; i < 8; i++) ov[i] = (bf16_t)o[i];
    *(bf16x8*)(yb + row * 512 + lane * 8) = ov;
  }
}

extern "C" void kernel_launch(void* const* d_in, const int* in_sizes, int n_in,
                              void* d_out, int out_size, void* d_ws, size_t ws_size,
                              hipStream_t stream) {
  (void)in_sizes; (void)n_in; (void)out_size; (void)ws_size;
  const float* Q   = (const float*)d_in[0];
  const float* K   = (const float*)d_in[1];
  const float* Wq  = (const float*)d_in[2];
  const float* bq  = (const float*)d_in[3];
  const float* Wk  = (const float*)d_in[4];
  const float* bk  = (const float*)d_in[5];
  const float* Wv  = (const float*)d_in[6];
  const float* bv  = (const float*)d_in[7];
  const float* Wo  = (const float*)d_in[8];
  const float* bo  = (const float*)d_in[9];
  const float* g0  = (const float*)d_in[10];
  const float* be0 = (const float*)d_in[11];
  const float* g1  = (const float*)d_in[12];
  const float* be1 = (const float*)d_in[13];
  float* outp = (float*)d_out;

  char* w = (char*)d_ws;
  bf16_t* Wt  = (bf16_t*)w;                    // 2 MB (4 x 512x512 bf16)
  bf16_t* Qb  = (bf16_t*)(w + (2ull << 20));   // 32 MB  (input Q bf16)   -> dead after qp
  bf16_t* Kb  = (bf16_t*)(w + (34ull << 20));  // 32 MB  (input K bf16)   -> dead after vp
  bf16_t* qp  = (bf16_t*)(w + (66ull << 20));  // 32 MB  (Q proj; residual source)
  bf16_t* kp  = (bf16_t*)(w + (98ull << 20));  // 32 MB  (K proj, pre-scaled)
  bf16_t* vp  = (bf16_t*)(w + (130ull << 20)); // 32 MB  (V proj)         -> dead after stats
  bf16_t* Vt  = Kb;                            // reuse: V'/l transposed [hb][64][1024]
  bf16_t* ohb = Qb;                            // reuse: attn out (no resid)
  bf16_t* x0b = vp;                            // reuse: LN0 out
  bf16_t* oh2 = kp;                            // reuse: out-proj+relu+resid

  cvt_bf16<<<dim3(8192, 2), 256, 0, stream>>>(Q, K, Qb, Kb);
  transpose_w<<<dim3(16, 16, 4), dim3(32, 8), 0, stream>>>(Wq, Wk, Wv, Wo, Wt);
  gemm_k<0><<<dim3(256, 4), 256, 0, stream>>>(Qb, Wt + 0 * (1 << 18), bq, 1.0f, qp);
  gemm_k<0><<<dim3(256, 4), 256, 0, stream>>>(Kb, Wt + 1 * (1 << 18), bk, SCALE, kp);
  gemm_k<0><<<dim3(256, 4), 256, 0, stream>>>(Kb, Wt + 2 * (1 << 18), bv, 1.0f, vp);
  attn_stats<<<2048, 256, 0, stream>>>(qp, kp, vp, Vt);
  attn_out<<<2048, 256, 0, stream>>>(qp, kp, Vt, ohb);
  ln_k<1, 0><<<8192, 256, 0, stream>>>(ohb, qp, g0, be0, x0b, nullptr);
  gemm_k<1><<<dim3(256, 4), 256, 0, stream>>>(x0b, Wt + 3 * (1 << 18), bo, 1.0f, oh2);
  ln_k<0, 1><<<8192, 256, 0, stream>>>(oh2, nullptr, g1, be1, nullptr, outp);
}

// Round 4
// 494.618 us; speedup vs baseline: 1.5279x; 1.0403x over previous
//
#include <hip/hip_runtime.h>

#define Bz  32
#define NQz 1024
#define NKz 1024
#define SCALE 0.04419417382415922f  // 1/sqrt(512)

typedef __bf16 bf16_t;
typedef bf16_t bf16x8 __attribute__((ext_vector_type(8)));
typedef bf16_t bf16x4 __attribute__((ext_vector_type(4)));
typedef float  f32x4  __attribute__((ext_vector_type(4)));

#define MFMA16(a, b, c) __builtin_amdgcn_mfma_f32_16x16x32_bf16(a, b, c, 0, 0, 0)

// async global->LDS DMA, 16B per lane; LDS dest = lptr + lane*16 (wave-uniform base)
__device__ __forceinline__ void gll16(const void* g, void* l) {
  __builtin_amdgcn_global_load_lds(
      (const __attribute__((address_space(1))) void*)g,
      (__attribute__((address_space(3))) void*)l, 16, 0, 0);
}

__device__ __forceinline__ bf16x8 cvt8(float4 a, float4 b) {
  bf16x8 r;
  r[0] = (bf16_t)a.x; r[1] = (bf16_t)a.y; r[2] = (bf16_t)a.z; r[3] = (bf16_t)a.w;
  r[4] = (bf16_t)b.x; r[5] = (bf16_t)b.y; r[6] = (bf16_t)b.z; r[7] = (bf16_t)b.w;
  return r;
}

// ---- transpose + bf16-convert the four 512x512 weight matrices: Wt[n][k] = W[k][n]
__global__ void transpose_w(const float* __restrict__ W0, const float* __restrict__ W1,
                            const float* __restrict__ W2, const float* __restrict__ W3,
                            bf16_t* __restrict__ out) {
  __shared__ float tile[32][33];
  const float* W = blockIdx.z == 0 ? W0 : blockIdx.z == 1 ? W1 : blockIdx.z == 2 ? W2 : W3;
  bf16_t* o = out + (size_t)blockIdx.z * 512 * 512;
  const int n0 = blockIdx.x * 32, k0 = blockIdx.y * 32;
  const int tx = threadIdx.x, ty = threadIdx.y;  // (32,8)
  for (int i = 0; i < 4; i++)
    tile[ty + i * 8][tx] = W[(size_t)(k0 + ty + i * 8) * 512 + n0 + tx];
  __syncthreads();
  for (int i = 0; i < 4; i++)
    o[(size_t)(n0 + ty + i * 8) * 512 + k0 + tx] = (bf16_t)tile[tx][ty + i * 8];
}

// ===================== projection GEMMs (A = fp32 input) =====================
// 128x128 tile. A f32 staged via VGPR+cvt into padded As; W staged via
// global_load_lds into XOR-swizzled flat Bs (granule g at pos g^((row>>1)&3)).
// DUAL=0: C0 = bf16((A@W + b0) * mult0), grid.y=4.
// DUAL=1: W spans [1024][512] (Wk||Wv); n0<512 -> C0 (bias b0, mult0),
//         else C1 (bias b1, mult 1). grid.y=8.
template <int DUAL>
__global__ __launch_bounds__(256) void gemm_f32a(const float* __restrict__ A,
                                                 const bf16_t* __restrict__ Wt,
                                                 const float* __restrict__ b0v,
                                                 const float* __restrict__ b1v,
                                                 float mult0,
                                                 bf16_t* __restrict__ C0,
                                                 bf16_t* __restrict__ C1) {
  __shared__ __align__(16) bf16_t As[128][40];
  __shared__ __align__(16) bf16_t Bs[128 * 32];
  const int t = threadIdx.x;
  const int wave = t >> 6, lane = t & 63;
  const int quad = lane >> 4, l16 = lane & 15;
  const int wm = wave & 1, wn = wave >> 1;
  const int m0 = blockIdx.x * 128, n0 = blockIdx.y * 128;
  const int r = t >> 1, half = t & 1;
  // DMA mapping: pass p -> row p*64 + wave*16 + (lane>>2), src granule (lane&3)^((lane>>3)&3)
  const int drow = lane >> 2;
  const int dg = (lane & 3) ^ ((lane >> 3) & 3);

  f32x4 acc[4][4] = {};

  for (int k0 = 0; k0 < 512; k0 += 32) {
    __syncthreads();
    for (int p = 0; p < 2; p++) {
      const bf16_t* src = Wt + (size_t)(n0 + p * 64 + wave * 16 + drow) * 512 + k0 + dg * 8;
      gll16(src, &Bs[(p * 256 + wave * 64) * 8]);
    }
    {
      const float* ap = A + (size_t)(m0 + r) * 512 + k0 + half * 16;
      float4 a0 = *(const float4*)(ap + 0);
      float4 a1 = *(const float4*)(ap + 4);
      float4 a2 = *(const float4*)(ap + 8);
      float4 a3 = *(const float4*)(ap + 12);
      *(bf16x8*)&As[r][half * 16 + 0] = cvt8(a0, a1);
      *(bf16x8*)&As[r][half * 16 + 8] = cvt8(a2, a3);
    }
    __syncthreads();
    bf16x8 af[4], bfv[4];
    for (int mt = 0; mt < 4; mt++)
      af[mt] = *(const bf16x8*)&As[wm * 64 + mt * 16 + l16][quad * 8];
    for (int nt = 0; nt < 4; nt++) {
      const int rB = wn * 64 + nt * 16 + l16;
      bfv[nt] = *(const bf16x8*)&Bs[rB * 32 + ((quad ^ ((rB >> 1) & 3)) * 8)];
    }
    for (int mt = 0; mt < 4; mt++)
      for (int nt = 0; nt < 4; nt++)
        acc[mt][nt] = MFMA16(af[mt], bfv[nt], acc[mt][nt]);
  }

  const float* bias = (!DUAL || n0 < 512) ? b0v : b1v;
  bf16_t* C = (!DUAL || n0 < 512) ? C0 : C1;
  const float mult = (!DUAL || n0 < 512) ? mult0 : 1.0f;
  const int nb = (!DUAL || n0 < 512) ? n0 : n0 - 512;
  for (int mt = 0; mt < 4; mt++) {
    for (int nt = 0; nt < 4; nt++) {
      const int row = m0 + wm * 64 + mt * 16 + quad * 4;
      const int col = nb + wn * 64 + nt * 16 + l16;
      const float bv = bias[col];
      for (int rg = 0; rg < 4; rg++)
        C[(size_t)(row + rg) * 512 + col] = (bf16_t)((acc[mt][nt][rg] + bv) * mult);
    }
  }
}

// ===================== output GEMM (A = bf16, resid+relu epilogue) ===========
__global__ __launch_bounds__(256) void gemm_bf16a(const bf16_t* __restrict__ A,
                                                  const bf16_t* __restrict__ Wt,
                                                  const float* __restrict__ bias,
                                                  bf16_t* __restrict__ C) {
  __shared__ __align__(16) bf16_t As[128][40];
  __shared__ __align__(16) bf16_t Bs[128 * 32];
  const int t = threadIdx.x;
  const int wave = t >> 6, lane = t & 63;
  const int quad = lane >> 4, l16 = lane & 15;
  const int wm = wave & 1, wn = wave >> 1;
  const int m0 = blockIdx.x * 128, n0 = blockIdx.y * 128;
  const int r = t >> 1, half = t & 1;
  const int drow = lane >> 2;
  const int dg = (lane & 3) ^ ((lane >> 3) & 3);

  f32x4 acc[4][4] = {};

  for (int k0 = 0; k0 < 512; k0 += 32) {
    __syncthreads();
    for (int p = 0; p < 2; p++) {
      const bf16_t* src = Wt + (size_t)(n0 + p * 64 + wave * 16 + drow) * 512 + k0 + dg * 8;
      gll16(src, &Bs[(p * 256 + wave * 64) * 8]);
    }
    {
      const bf16_t* ap = A + (size_t)(m0 + r) * 512 + k0 + half * 16;
      *(bf16x8*)&As[r][half * 16 + 0] = *(const bf16x8*)(ap + 0);
      *(bf16x8*)&As[r][half * 16 + 8] = *(const bf16x8*)(ap + 8);
    }
    __syncthreads();
    bf16x8 af[4], bfv[4];
    for (int mt = 0; mt < 4; mt++)
      af[mt] = *(const bf16x8*)&As[wm * 64 + mt * 16 + l16][quad * 8];
    for (int nt = 0; nt < 4; nt++) {
      const int rB = wn * 64 + nt * 16 + l16;
      bfv[nt] = *(const bf16x8*)&Bs[rB * 32 + ((quad ^ ((rB >> 1) & 3)) * 8)];
    }
    for (int mt = 0; mt < 4; mt++)
      for (int nt = 0; nt < 4; nt++)
        acc[mt][nt] = MFMA16(af[mt], bfv[nt], acc[mt][nt]);
  }

  for (int mt = 0; mt < 4; mt++) {
    for (int nt = 0; nt < 4; nt++) {
      const int row = m0 + wm * 64 + mt * 16 + quad * 4;
      const int col = n0 + wn * 64 + nt * 16 + l16;
      const float bv = bias[col];
      for (int rg = 0; rg < 4; rg++) {
        float v = acc[mt][nt][rg] + bv;
        float x = (float)A[(size_t)(row + rg) * 512 + col];
        C[(size_t)(row + rg) * 512 + col] = (bf16_t)(x + fmaxf(v, 0.f));
      }
    }
  }
}

// ---- stats: l_k = sum_q exp(s[q,k]) (kp pre-scaled); writes Vt[hb][d][k] = V[k][d]/l_k.
// Grid 2048 (XCD-swizzled). K A-frags in regs; Q tiles DMA-staged (XOR swizzle g^(row&7)).
__global__ __launch_bounds__(256) void attn_stats(const bf16_t* __restrict__ qp,
                                                  const bf16_t* __restrict__ kp,
                                                  const bf16_t* __restrict__ vp,
                                                  bf16_t* __restrict__ Vt) {
  __shared__ __align__(16) bf16_t Vs[128][72];
  __shared__ __align__(16) bf16_t Qs[64 * 64];
  __shared__ float ls[128];
  const int t = threadIdx.x;
  const int wave = t >> 6, lane = t & 63;
  const int quad = lane >> 4, l16 = lane & 15;
  const int id = blockIdx.x;
  const int kb = ((id >> 3) & 7) * 128;
  const int hb = (id & 7) * 32 + (id >> 6);
  const int h = hb >> 5, b = hb & 31;
  const bf16_t* qbase = qp + (size_t)b * NQz * 512 + h * 64;
  const bf16_t* kbase = kp + (size_t)b * NKz * 512 + h * 64;
  // DMA mapping (8 granules/row): row p*32+wave*8+(lane>>3), src granule (lane&7)^(lane>>3)
  const int drow = lane >> 3;
  const int dg = (lane & 7) ^ drow;

  {  // stage V block for the epilogue transpose
    const int r = t >> 1, half = t & 1;
    const bf16_t* vr = vp + (size_t)b * NKz * 512 + (size_t)(kb + r) * 512 + h * 64 + half * 32;
    *(bf16x8*)&Vs[r][half * 32 + 0]  = *(const bf16x8*)(vr + 0);
    *(bf16x8*)&Vs[r][half * 32 + 8]  = *(const bf16x8*)(vr + 8);
    *(bf16x8*)&Vs[r][half * 32 + 16] = *(const bf16x8*)(vr + 16);
    *(bf16x8*)&Vs[r][half * 32 + 24] = *(const bf16x8*)(vr + 24);
  }

  bf16x8 aK[2][2];
  for (int mt = 0; mt < 2; mt++) {
    const bf16_t* kr = kbase + (size_t)(kb + wave * 32 + mt * 16 + l16) * 512 + quad * 8;
    aK[mt][0] = *(const bf16x8*)kr;
    aK[mt][1] = *(const bf16x8*)(kr + 32);
  }

  f32x4 lacc[2] = {};
  for (int q0 = 0; q0 < NQz; q0 += 64) {
    __syncthreads();
    for (int p = 0; p < 2; p++) {
      const bf16_t* src = qbase + (size_t)(q0 + p * 32 + wave * 8 + drow) * 512 + dg * 8;
      gll16(src, &Qs[(p * 256 + wave * 64) * 8]);
    }
    __syncthreads();
    for (int nt = 0; nt < 4; nt++) {
      const int rQ = nt * 16 + l16;
      bf16x8 b0 = *(const bf16x8*)&Qs[rQ * 64 + ((quad ^ (rQ & 7)) * 8)];
      bf16x8 b1 = *(const bf16x8*)&Qs[rQ * 64 + (((quad + 4) ^ (rQ & 7)) * 8)];
      for (int mt = 0; mt < 2; mt++) {
        f32x4 s = {0.f, 0.f, 0.f, 0.f};
        s = MFMA16(aK[mt][0], b0, s);
        s = MFMA16(aK[mt][1], b1, s);
        lacc[mt][0] += __expf(s[0]);
        lacc[mt][1] += __expf(s[1]);
        lacc[mt][2] += __expf(s[2]);
        lacc[mt][3] += __expf(s[3]);
      }
    }
  }
  for (int mt = 0; mt < 2; mt++) {
    for (int rg = 0; rg < 4; rg++) {
      float v = lacc[mt][rg];
      v += __shfl_xor(v, 1);
      v += __shfl_xor(v, 2);
      v += __shfl_xor(v, 4);
      v += __shfl_xor(v, 8);
      if (l16 == 0) ls[wave * 32 + mt * 16 + quad * 4 + rg] = 1.0f / v;
    }
  }
  __syncthreads();
  const int d = t >> 2, kc = (t & 3) * 32;
  bf16_t* vtr = Vt + (size_t)hb * 64 * 1024 + (size_t)d * 1024 + kb + kc;
  for (int c = 0; c < 4; c++) {
    bf16x8 o;
    for (int j = 0; j < 8; j++)
      o[j] = (bf16_t)((float)Vs[kc + c * 8 + j][d] * ls[kc + c * 8 + j]);
    *(bf16x8*)(vtr + c * 8) = o;
  }
}

// ---- attn_out: O[q,d] = sum_k exp(s[q,k]) * Vt[d,k].  Grid 2048 (XCD-swizzled).
// K-tile + Vt-tile DMA-staged (XOR swizzle); Q B-frags in regs; P via wave-private
// Ps rows (b64 writes, no extra barrier).
__global__ __launch_bounds__(256) void attn_out(const bf16_t* __restrict__ qp,
                                                const bf16_t* __restrict__ kp,
                                                const bf16_t* __restrict__ Vt,
                                                bf16_t* __restrict__ oh) {
  __shared__ __align__(16) bf16_t Ks[64 * 64];
  __shared__ __align__(16) bf16_t Vts[64 * 64];
  __shared__ __align__(16) bf16_t Ps[128][72];
  const int t = threadIdx.x;
  const int wave = t >> 6, lane = t & 63;
  const int quad = lane >> 4, l16 = lane & 15;
  const int id = blockIdx.x;
  const int qt = (id >> 3) & 7;
  const int hb = (id & 7) * 32 + (id >> 6);
  const int h = hb >> 5, b = hb & 31;
  const int q0 = qt * 128;
  const bf16_t* qbase = qp + (size_t)b * NQz * 512 + h * 64;
  const bf16_t* kbase = kp + (size_t)b * NKz * 512 + h * 64;
  const bf16_t* vtbase = Vt + (size_t)hb * 64 * 1024;
  const int drow = lane >> 3;
  const int dg = (lane & 7) ^ drow;

  bf16x8 bQ[2][2];
  for (int nt = 0; nt < 2; nt++) {
    const bf16_t* qr = qbase + (size_t)(q0 + wave * 32 + nt * 16 + l16) * 512 + quad * 8;
    bQ[nt][0] = *(const bf16x8*)qr;
    bQ[nt][1] = *(const bf16x8*)(qr + 32);
  }

  f32x4 acc[2][4] = {};
  for (int kk = 0; kk < NKz; kk += 64) {
    __syncthreads();
    for (int p = 0; p < 2; p++) {
      const bf16_t* ksrc = kbase + (size_t)(kk + p * 32 + wave * 8 + drow) * 512 + dg * 8;
      gll16(ksrc, &Ks[(p * 256 + wave * 64) * 8]);
      const bf16_t* vsrc = vtbase + (size_t)(p * 32 + wave * 8 + drow) * 1024 + kk + dg * 8;
      gll16(vsrc, &Vts[(p * 256 + wave * 64) * 8]);
    }
    __syncthreads();
    // S^T: m = k (A-frag from Ks), n = q (regs). C rows = 4 consecutive k -> b64 pack.
    for (int mt = 0; mt < 4; mt++) {
      const int rK = mt * 16 + l16;
      bf16x8 a0 = *(const bf16x8*)&Ks[rK * 64 + ((quad ^ (rK & 7)) * 8)];
      bf16x8 a1 = *(const bf16x8*)&Ks[rK * 64 + (((quad + 4) ^ (rK & 7)) * 8)];
      for (int nt = 0; nt < 2; nt++) {
        f32x4 s = {0.f, 0.f, 0.f, 0.f};
        s = MFMA16(a0, bQ[nt][0], s);
        s = MFMA16(a1, bQ[nt][1], s);
        bf16x4 pk;
        pk[0] = (bf16_t)__expf(s[0]);
        pk[1] = (bf16_t)__expf(s[1]);
        pk[2] = (bf16_t)__expf(s[2]);
        pk[3] = (bf16_t)__expf(s[3]);
        *(bf16x4*)&Ps[wave * 32 + nt * 16 + l16][mt * 16 + quad * 4] = pk;
      }
    }
    // PV: A-frag = Ps rows (wave-private, b128), B-frag = Vts rows (swizzled b128).
    bf16x8 aP[2][2];
    for (int mt = 0; mt < 2; mt++) {
      aP[mt][0] = *(const bf16x8*)&Ps[wave * 32 + mt * 16 + l16][quad * 8];
      aP[mt][1] = *(const bf16x8*)&Ps[wave * 32 + mt * 16 + l16][quad * 8 + 32];
    }
    for (int nd = 0; nd < 4; nd++) {
      const int rV = nd * 16 + l16;
      bf16x8 b0 = *(const bf16x8*)&Vts[rV * 64 + ((quad ^ (rV & 7)) * 8)];
      bf16x8 b1 = *(const bf16x8*)&Vts[rV * 64 + (((quad + 4) ^ (rV & 7)) * 8)];
      for (int mt = 0; mt < 2; mt++) {
        acc[mt][nd] = MFMA16(aP[mt][0], b0, acc[mt][nd]);
        acc[mt][nd] = MFMA16(aP[mt][1], b1, acc[mt][nd]);
      }
    }
  }
  for (int mt = 0; mt < 2; mt++)
    for (int nd = 0; nd < 4; nd++)
      for (int rg = 0; rg < 4; rg++)
        Ps[wave * 32 + mt * 16 + quad * 4 + rg][nd * 16 + l16] = (bf16_t)acc[mt][nd][rg];
  const int row = wave * 32 + (lane >> 1), cc = (lane & 1) * 32;
  bf16_t* orow = oh + ((size_t)b * NQz + q0 + row) * 512 + h * 64 + cc;
  for (int c = 0; c < 4; c++)
    *(bf16x8*)(orow + c * 8) = *(const bf16x8*)&Ps[row][cc + c * 8];
}

// ---- LayerNorm over 512 cols, one wave per row, bf16 in.
template <int RES, int F32OUT>
__global__ __launch_bounds__(256) void ln_k(const bf16_t* __restrict__ x,
                                            const bf16_t* __restrict__ res,
                                            const float* __restrict__ g,
                                            const float* __restrict__ be,
                                            bf16_t* __restrict__ yb,
                                            float* __restrict__ yf) {
  const int wave = threadIdx.x >> 6, lane = threadIdx.x & 63;
  const size_t row = (size_t)blockIdx.x * 4 + wave;
  bf16x8 xv = *(const bf16x8*)(x + row * 512 + lane * 8);
  float xf[8];
  for (int i = 0; i < 8; i++) xf[i] = (float)xv[i];
  if (RES) {
    bf16x8 rv = *(const bf16x8*)(res + row * 512 + lane * 8);
    for (int i = 0; i < 8; i++) xf[i] += (float)rv[i];
  }
  float s = 0.f, sq = 0.f;
  for (int i = 0; i < 8; i++) { s += xf[i]; sq += xf[i] * xf[i]; }
  for (int off = 1; off < 64; off <<= 1) {
    s += __shfl_xor(s, off);
    sq += __shfl_xor(sq, off);
  }
  const float mu = s * (1.0f / 512.0f);
  const float var = sq * (1.0f / 512.0f) - mu * mu;
  const float rstd = rsqrtf(var + 1e-5f);
  float4 gv0 = *(const float4*)(g + lane * 8);
  float4 gv1 = *(const float4*)(g + lane * 8 + 4);
  float4 bv0 = *(const float4*)(be + lane * 8);
  float4 bv1 = *(const float4*)(be + lane * 8 + 4);
  float gg[8] = {gv0.x, gv0.y, gv0.z, gv0.w, gv1.x, gv1.y, gv1.z, gv1.w};
  float bb[8] = {bv0.x, bv0.y, bv0.z, bv0.w, bv1.x, bv1.y, bv1.z, bv1.w};
  float o[8];
  for (int i = 0; i < 8; i++) o[i] = (xf[i] - mu) * rstd * gg[i] + bb[i];
  if (F32OUT) {
    float4 o0 = {o[0], o[1], o[2], o[3]}, o1 = {o[4], o[5], o[6], o[7]};
    *(float4*)(yf + row * 512 + lane * 8) = o0;
    *(float4*)(yf + row * 512 + lane * 8 + 4) = o1;
  } else {
    bf16x8 ov;
    for (int i = 0; i < 8; i++) ov[i] = (bf16_t)o[i];
    *(bf16x8*)(yb + row * 512 + lane * 8) = ov;
  }
}

extern "C" void kernel_launch(void* const* d_in, const int* in_sizes, int n_in,
                              void* d_out, int out_size, void* d_ws, size_t ws_size,
                              hipStream_t stream) {
  (void)in_sizes; (void)n_in; (void)out_size; (void)ws_size;
  const float* Q   = (const float*)d_in[0];
  const float* K   = (const float*)d_in[1];
  const float* Wq  = (const float*)d_in[2];
  const float* bq  = (const float*)d_in[3];
  const float* Wk  = (const float*)d_in[4];
  const float* bk  = (const float*)d_in[5];
  const float* Wv  = (const float*)d_in[6];
  const float* bv  = (const float*)d_in[7];
  const float* Wo  = (const float*)d_in[8];
  const float* bo  = (const float*)d_in[9];
  const float* g0  = (const float*)d_in[10];
  const float* be0 = (const float*)d_in[11];
  const float* g1  = (const float*)d_in[12];
  const float* be1 = (const float*)d_in[13];
  float* outp = (float*)d_out;

  char* w = (char*)d_ws;
  bf16_t* Wt  = (bf16_t*)w;                     // 2 MB (4 x 512x512 bf16)
  bf16_t* qp  = (bf16_t*)(w + (2ull << 20));    // 32 MB (Q proj; residual source)
  bf16_t* kp  = (bf16_t*)(w + (34ull << 20));   // 32 MB (K proj, pre-scaled)
  bf16_t* vp  = (bf16_t*)(w + (66ull << 20));   // 32 MB (V proj, dead after stats)
  bf16_t* Vt  = (bf16_t*)(w + (98ull << 20));   // 32 MB (V'/l transposed [hb][64][1024])
  bf16_t* ohb = (bf16_t*)(w + (130ull << 20));  // 32 MB (attn out, no resid)
  bf16_t* x0b = vp;                             // reuse: LN0 out
  bf16_t* oh2 = kp;                             // reuse: out-proj+relu+resid

  transpose_w<<<dim3(16, 16, 4), dim3(32, 8), 0, stream>>>(Wq, Wk, Wv, Wo, Wt);
  gemm_f32a<0><<<dim3(256, 4), 256, 0, stream>>>(Q, Wt, bq, nullptr, 1.0f, qp, nullptr);
  gemm_f32a<1><<<dim3(256, 8), 256, 0, stream>>>(K, Wt + (1 << 18), bk, bv, SCALE, kp, vp);
  attn_stats<<<2048, 256, 0, stream>>>(qp, kp, vp, Vt);
  attn_out<<<2048, 256, 0, stream>>>(qp, kp, Vt, ohb);
  ln_k<1, 0><<<8192, 256, 0, stream>>>(ohb, qp, g0, be0, x0b, nullptr);
  gemm_bf16a<<<dim3(256, 4), 256, 0, stream>>>(x0b, Wt + 3 * (1 << 18), bo, oh2);
  ln_k<0, 1><<<8192, 256, 0, stream>>>(oh2, nullptr, g1, be1, nullptr, outp);
}